// Round 1
// baseline (468.681 us; speedup 1.0000x reference)
//
#include <hip/hip_runtime.h>
#include <hip/hip_bf16.h>
#include <math.h>

#define DIM 1024
#define HID 2048
#define NEXP 8
#define NTOK 1024   // B*T = 2*512
#define TOPK 2

#define BM 64
#define BN 64
#define BK 32
#define XPAD 68     // row stride (floats) for transposed LDS tiles; 68*4B = 272B, 16B-aligned

// ---------------- router: logits -> top2 -> renormalized weights -> expert lists ----------------
__global__ __launch_bounds__(64) void router_kernel(
    const float* __restrict__ x, const float* __restrict__ rw,
    int* __restrict__ counts, int* __restrict__ slot_list, float* __restrict__ w_list)
{
    int t = blockIdx.x;
    int lane = threadIdx.x;
    const float* xr = x + (size_t)t * DIM;
    float acc[NEXP];
#pragma unroll
    for (int e = 0; e < NEXP; ++e) acc[e] = 0.f;
    for (int d = lane; d < DIM; d += 64) {
        float xv = xr[d];
#pragma unroll
        for (int e = 0; e < NEXP; ++e) acc[e] += xv * rw[e * DIM + d];
    }
#pragma unroll
    for (int off = 32; off > 0; off >>= 1) {
#pragma unroll
        for (int e = 0; e < NEXP; ++e) acc[e] += __shfl_down(acc[e], off, 64);
    }
    if (lane == 0) {
        int i1 = 0;
#pragma unroll
        for (int e = 1; e < NEXP; ++e) if (acc[e] > acc[i1]) i1 = e;
        int i2 = -1;
#pragma unroll
        for (int e = 0; e < NEXP; ++e) {
            if (e == i1) continue;
            if (i2 < 0 || acc[e] > acc[i2]) i2 = e;
        }
        // softmax-renorm over the two selected logits
        float w1 = 1.f / (1.f + expf(acc[i2] - acc[i1]));
        float w2 = 1.f - w1;
        int p1 = atomicAdd(&counts[i1], 1);
        slot_list[i1 * NTOK + p1] = t * 2 + 0;
        w_list[i1 * NTOK + p1] = w1;
        int p2 = atomicAdd(&counts[i2], 1);
        slot_list[i2 * NTOK + p2] = t * 2 + 1;
        w_list[i2 * NTOK + p2] = w2;
    }
}

// ---------------- gate+up grouped GEMM: h = w_pair * silu(x@Wg^T) * (x@Wu^T) ----------------
__global__ __launch_bounds__(256) void gateup_kernel(
    const float* __restrict__ x, const float* __restrict__ wg, const float* __restrict__ wu,
    const int* __restrict__ counts, const int* __restrict__ slot_list, const float* __restrict__ w_list,
    float* __restrict__ h_buf)
{
    int e = blockIdx.y;
    int n_e = counts[e];
    if (n_e == 0) return;
    int hbase = blockIdx.x * BN;
    const float* WG = wg + (size_t)e * HID * DIM;
    const float* WU = wu + (size_t)e * HID * DIM;
    const int* sl = slot_list + e * NTOK;
    const float* wl = w_list + e * NTOK;

    __shared__ float Xs[BK][XPAD];
    __shared__ float Gs[BK][XPAD];
    __shared__ float Us[BK][XPAD];

    int tid = threadIdx.x;
    int tm = (tid & 15) * 4;   // token dir
    int tn = (tid >> 4) * 4;   // h dir

    for (int m0 = blockIdx.z * BM; m0 < n_e; m0 += gridDim.z * BM) {
        int rows = n_e - m0; if (rows > BM) rows = BM;
        float accg[4][4] = {{0.f}};
        float accu[4][4] = {{0.f}};
        for (int k0 = 0; k0 < DIM; k0 += BK) {
#pragma unroll
            for (int p = 0; p < 2; ++p) {
                int idx = p * 256 + tid;   // 0..511
                int r = idx >> 3;          // 0..63
                int c = (idx & 7) * 4;     // 0,4,...,28
                float4 xv = make_float4(0.f, 0.f, 0.f, 0.f);
                if (r < rows) {
                    int tok = sl[m0 + r] >> 1;
                    xv = *(const float4*)(x + (size_t)tok * DIM + k0 + c);
                }
                Xs[c + 0][r] = xv.x; Xs[c + 1][r] = xv.y; Xs[c + 2][r] = xv.z; Xs[c + 3][r] = xv.w;
                float4 gv = *(const float4*)(WG + (size_t)(hbase + r) * DIM + k0 + c);
                Gs[c + 0][r] = gv.x; Gs[c + 1][r] = gv.y; Gs[c + 2][r] = gv.z; Gs[c + 3][r] = gv.w;
                float4 uv = *(const float4*)(WU + (size_t)(hbase + r) * DIM + k0 + c);
                Us[c + 0][r] = uv.x; Us[c + 1][r] = uv.y; Us[c + 2][r] = uv.z; Us[c + 3][r] = uv.w;
            }
            __syncthreads();
#pragma unroll
            for (int kk = 0; kk < BK; ++kk) {
                float4 xv = *(const float4*)&Xs[kk][tm];
                float4 gv = *(const float4*)&Gs[kk][tn];
                float4 uv = *(const float4*)&Us[kk][tn];
                float xa[4] = {xv.x, xv.y, xv.z, xv.w};
                float ga[4] = {gv.x, gv.y, gv.z, gv.w};
                float ua[4] = {uv.x, uv.y, uv.z, uv.w};
#pragma unroll
                for (int i = 0; i < 4; ++i)
#pragma unroll
                    for (int j = 0; j < 4; ++j) {
                        accg[i][j] += xa[i] * ga[j];
                        accu[i][j] += xa[i] * ua[j];
                    }
            }
            __syncthreads();
        }
#pragma unroll
        for (int i = 0; i < 4; ++i) {
            int r = tm + i;
            if (m0 + r < n_e) {
                int slot = sl[m0 + r];
                float w = wl[m0 + r];
                float4 hv;
                {
                    float g = accg[i][0], u = accu[i][0];
                    hv.x = w * (g / (1.f + expf(-g))) * u;
                }
                {
                    float g = accg[i][1], u = accu[i][1];
                    hv.y = w * (g / (1.f + expf(-g))) * u;
                }
                {
                    float g = accg[i][2], u = accu[i][2];
                    hv.z = w * (g / (1.f + expf(-g))) * u;
                }
                {
                    float g = accg[i][3], u = accu[i][3];
                    hv.w = w * (g / (1.f + expf(-g))) * u;
                }
                *(float4*)(h_buf + (size_t)slot * HID + hbase + tn) = hv;
            }
        }
    }
}

// ---------------- down grouped GEMM: y[pair] = h[pair] @ Wd^T ----------------
__global__ __launch_bounds__(256) void down_kernel(
    const float* __restrict__ h_buf, const float* __restrict__ wd,
    const int* __restrict__ counts, const int* __restrict__ slot_list,
    float* __restrict__ ybuf)
{
    int e = blockIdx.y;
    int n_e = counts[e];
    if (n_e == 0) return;
    int dbase = blockIdx.x * BN;
    const float* WD = wd + (size_t)e * DIM * HID;
    const int* sl = slot_list + e * NTOK;

    __shared__ float Hs[BK][XPAD];
    __shared__ float Ws[BK][XPAD];

    int tid = threadIdx.x;
    int tm = (tid & 15) * 4;
    int tn = (tid >> 4) * 4;

    for (int m0 = blockIdx.z * BM; m0 < n_e; m0 += gridDim.z * BM) {
        int rows = n_e - m0; if (rows > BM) rows = BM;
        float acc[4][4] = {{0.f}};
        for (int k0 = 0; k0 < HID; k0 += BK) {
#pragma unroll
            for (int p = 0; p < 2; ++p) {
                int idx = p * 256 + tid;
                int r = idx >> 3;
                int c = (idx & 7) * 4;
                float4 hv = make_float4(0.f, 0.f, 0.f, 0.f);
                if (r < rows) {
                    int slot = sl[m0 + r];
                    hv = *(const float4*)(h_buf + (size_t)slot * HID + k0 + c);
                }
                Hs[c + 0][r] = hv.x; Hs[c + 1][r] = hv.y; Hs[c + 2][r] = hv.z; Hs[c + 3][r] = hv.w;
                float4 wv = *(const float4*)(WD + (size_t)(dbase + r) * HID + k0 + c);
                Ws[c + 0][r] = wv.x; Ws[c + 1][r] = wv.y; Ws[c + 2][r] = wv.z; Ws[c + 3][r] = wv.w;
            }
            __syncthreads();
#pragma unroll
            for (int kk = 0; kk < BK; ++kk) {
                float4 hv = *(const float4*)&Hs[kk][tm];
                float4 wv = *(const float4*)&Ws[kk][tn];
                float ha[4] = {hv.x, hv.y, hv.z, hv.w};
                float wa[4] = {wv.x, wv.y, wv.z, wv.w};
#pragma unroll
                for (int i = 0; i < 4; ++i)
#pragma unroll
                    for (int j = 0; j < 4; ++j)
                        acc[i][j] += ha[i] * wa[j];
            }
            __syncthreads();
        }
#pragma unroll
        for (int i = 0; i < 4; ++i) {
            int r = tm + i;
            if (m0 + r < n_e) {
                int slot = sl[m0 + r];
                float4 yv = make_float4(acc[i][0], acc[i][1], acc[i][2], acc[i][3]);
                *(float4*)(ybuf + (size_t)slot * DIM + dbase + tn) = yv;
            }
        }
    }
}

// ---------------- combine: out[t] = y[2t] + y[2t+1] (weights already folded into h) ----------------
__global__ __launch_bounds__(256) void combine_kernel(const float* __restrict__ ybuf, float* __restrict__ out)
{
    int i = blockIdx.x * 256 + threadIdx.x;   // over NTOK*DIM/4
    int t = i >> 8;            // DIM/4 = 256 float4 per row
    int c = i & 255;
    const float4* ya = (const float4*)(ybuf + (size_t)(2 * t) * DIM) + c;
    const float4* yb = (const float4*)(ybuf + (size_t)(2 * t + 1) * DIM) + c;
    float4 a = *ya, b = *yb, r;
    r.x = a.x + b.x; r.y = a.y + b.y; r.z = a.z + b.z; r.w = a.w + b.w;
    ((float4*)(out + (size_t)t * DIM))[c] = r;
}

extern "C" void kernel_launch(void* const* d_in, const int* in_sizes, int n_in,
                              void* d_out, int out_size, void* d_ws, size_t ws_size,
                              hipStream_t stream) {
    const float* x  = (const float*)d_in[0];
    const float* rw = (const float*)d_in[1];
    const float* wg = (const float*)d_in[2];
    const float* wu = (const float*)d_in[3];
    const float* wd = (const float*)d_in[4];
    float* out = (float*)d_out;

    char* ws = (char*)d_ws;
    int* counts      = (int*)ws;                                   // 8 ints
    int* slot_list   = (int*)(ws + 256);                           // 32 KB
    float* w_list    = (float*)(ws + 256 + NEXP * NTOK * 4);       // 32 KB
    float* h_buf     = (float*)(ws + 256 + 2 * NEXP * NTOK * 4);   // N*K*H*4 = 16 MB
    float* ybuf      = (float*)((char*)h_buf + (size_t)NTOK * TOPK * HID * 4); // 8 MB

    hipMemsetAsync(counts, 0, NEXP * sizeof(int), stream);
    router_kernel<<<NTOK, 64, 0, stream>>>(x, rw, counts, slot_list, w_list);
    gateup_kernel<<<dim3(HID / BN, NEXP, 4), 256, 0, stream>>>(x, wg, wu, counts, slot_list, w_list, h_buf);
    down_kernel<<<dim3(DIM / BN, NEXP, 8), 256, 0, stream>>>(h_buf, wd, counts, slot_list, ybuf);
    combine_kernel<<<NTOK * DIM / 4 / 256, 256, 0, stream>>>(ybuf, out);
}

// Round 2
// 297.941 us; speedup vs baseline: 1.5731x; 1.5731x over previous
//
#include <hip/hip_runtime.h>
#include <hip/hip_bf16.h>
#include <math.h>

#define DIM 1024
#define HID 2048
#define NEXP 8
#define NTOK 1024   // B*T
#define TOPK 2

typedef __attribute__((ext_vector_type(4))) float f32x4;
typedef __attribute__((ext_vector_type(8))) short bf16x8;
typedef __attribute__((ext_vector_type(4))) short bf16x4;

__device__ inline bf16x4 cvt4(f32x4 v) {
    bf16x4 r;
#pragma unroll
    for (int i = 0; i < 4; ++i) {
        union { float f; unsigned u; } t; t.f = v[i];
        unsigned b = t.u + 0x7fffu + ((t.u >> 16) & 1u);   // round-to-nearest-even
        r[i] = (short)(b >> 16);
    }
    return r;
}

// ---------------- router: logits -> top2 -> renormalized weights -> expert lists ----------------
__global__ __launch_bounds__(64) void router_kernel(
    const float* __restrict__ x, const float* __restrict__ rw,
    int* __restrict__ counts, int* __restrict__ slot_list, float* __restrict__ w_list)
{
    int t = blockIdx.x;
    int lane = threadIdx.x;
    const float* xr = x + (size_t)t * DIM;
    float acc[NEXP];
#pragma unroll
    for (int e = 0; e < NEXP; ++e) acc[e] = 0.f;
    for (int d = lane; d < DIM; d += 64) {
        float xv = xr[d];
#pragma unroll
        for (int e = 0; e < NEXP; ++e) acc[e] += xv * rw[e * DIM + d];
    }
#pragma unroll
    for (int off = 32; off > 0; off >>= 1) {
#pragma unroll
        for (int e = 0; e < NEXP; ++e) acc[e] += __shfl_down(acc[e], off, 64);
    }
    if (lane == 0) {
        int i1 = 0;
#pragma unroll
        for (int e = 1; e < NEXP; ++e) if (acc[e] > acc[i1]) i1 = e;
        int i2 = -1;
#pragma unroll
        for (int e = 0; e < NEXP; ++e) {
            if (e == i1) continue;
            if (i2 < 0 || acc[e] > acc[i2]) i2 = e;
        }
        float w1 = 1.f / (1.f + expf(acc[i2] - acc[i1]));   // softmax renorm over top-2
        float w2 = 1.f - w1;
        int p1 = atomicAdd(&counts[i1], 1);
        slot_list[i1 * NTOK + p1] = t * 2 + 0;
        w_list[i1 * NTOK + p1] = w1;
        int p2 = atomicAdd(&counts[i2], 1);
        slot_list[i2 * NTOK + p2] = t * 2 + 1;
        w_list[i2 * NTOK + p2] = w2;
    }
}

// ---------------- gate+up grouped MFMA GEMM: h = w_pair * silu(x@Wg^T) * (x@Wu^T), bf16 out ----------------
#define GU_BM 64
#define GU_BN 128
#define GU_BK 64
#define LDK 72   // padded K-stride in shorts: 144B rows -> ~2-way read conflicts (free)

__global__ __launch_bounds__(256) void gateup_mfma(
    const float* __restrict__ x, const float* __restrict__ wg, const float* __restrict__ wu,
    const int* __restrict__ counts, const int* __restrict__ slot_list, const float* __restrict__ w_list,
    __hip_bfloat16* __restrict__ h_buf)
{
    __shared__ short Xs[GU_BM * LDK];
    __shared__ short Gs[GU_BN * LDK];
    __shared__ short Us[GU_BN * LDK];

    int e = blockIdx.y;
    int n_e = counts[e];
    if (n_e == 0) return;
    int hbase = blockIdx.x * GU_BN;
    const float* WG = wg + (size_t)e * HID * DIM;
    const float* WU = wu + (size_t)e * HID * DIM;
    const int* sl = slot_list + e * NTOK;
    const float* wl = w_list + e * NTOK;

    int tid = threadIdx.x;
    int lane = tid & 63;
    int wave = tid >> 6;
    int wm = wave >> 1;      // 0..1 (token dir)
    int wn = wave & 1;       // 0..1 (h dir)
    int fr = lane & 15;
    int fq = lane >> 4;      // 0..3

    for (int m0 = blockIdx.z * GU_BM; m0 < n_e; m0 += gridDim.z * GU_BM) {
        int rows = n_e - m0; if (rows > GU_BM) rows = GU_BM;
        f32x4 accg[2][4], accu[2][4];
#pragma unroll
        for (int i = 0; i < 2; ++i)
#pragma unroll
            for (int j = 0; j < 4; ++j) { accg[i][j] = (f32x4)(0.f); accu[i][j] = (f32x4)(0.f); }

        for (int k0 = 0; k0 < DIM; k0 += GU_BK) {
            // stage X tile (gathered rows, f32 -> bf16)
#pragma unroll
            for (int p = 0; p < 4; ++p) {
                int idx = p * 256 + tid;      // 0..1023
                int r = idx >> 4;             // 0..63
                int c4 = idx & 15;            // float4 within row
                f32x4 v = (f32x4)(0.f);
                if (r < rows) {
                    int tok = sl[m0 + r] >> 1;
                    v = *(const f32x4*)(x + (size_t)tok * DIM + k0 + c4 * 4);
                }
                *(bf16x4*)&Xs[r * LDK + c4 * 4] = cvt4(v);
            }
            // stage WG / WU tiles (f32 -> bf16)
#pragma unroll
            for (int p = 0; p < 8; ++p) {
                int idx = p * 256 + tid;      // 0..2047
                int r = idx >> 4;             // 0..127
                int c4 = idx & 15;
                f32x4 g = *(const f32x4*)(WG + (size_t)(hbase + r) * DIM + k0 + c4 * 4);
                f32x4 u = *(const f32x4*)(WU + (size_t)(hbase + r) * DIM + k0 + c4 * 4);
                *(bf16x4*)&Gs[r * LDK + c4 * 4] = cvt4(g);
                *(bf16x4*)&Us[r * LDK + c4 * 4] = cvt4(u);
            }
            __syncthreads();
#pragma unroll
            for (int kk = 0; kk < 2; ++kk) {
                int kof = kk * 32 + fq * 8;
                bf16x8 a[2], bg[4], bu[4];
#pragma unroll
                for (int i = 0; i < 2; ++i)
                    a[i] = *(const bf16x8*)&Xs[(wm * 32 + i * 16 + fr) * LDK + kof];
#pragma unroll
                for (int j = 0; j < 4; ++j) {
                    bg[j] = *(const bf16x8*)&Gs[(wn * 64 + j * 16 + fr) * LDK + kof];
                    bu[j] = *(const bf16x8*)&Us[(wn * 64 + j * 16 + fr) * LDK + kof];
                }
#pragma unroll
                for (int i = 0; i < 2; ++i)
#pragma unroll
                    for (int j = 0; j < 4; ++j) {
                        accg[i][j] = __builtin_amdgcn_mfma_f32_16x16x32_bf16(a[i], bg[j], accg[i][j], 0, 0, 0);
                        accu[i][j] = __builtin_amdgcn_mfma_f32_16x16x32_bf16(a[i], bu[j], accu[i][j], 0, 0, 0);
                    }
            }
            __syncthreads();
        }
        // epilogue: h = w * silu(g) * u  -> bf16 h_buf[slot][h]
#pragma unroll
        for (int i = 0; i < 2; ++i) {
            int rbase = wm * 32 + i * 16 + fq * 4;
#pragma unroll
            for (int reg = 0; reg < 4; ++reg) {
                int r = rbase + reg;
                if (m0 + r < n_e) {
                    int slot = sl[m0 + r];
                    float w = wl[m0 + r];
#pragma unroll
                    for (int j = 0; j < 4; ++j) {
                        float g = accg[i][j][reg];
                        float u = accu[i][j][reg];
                        float h = w * (g / (1.f + expf(-g))) * u;
                        h_buf[(size_t)slot * HID + hbase + wn * 64 + j * 16 + fr] = __float2bfloat16(h);
                    }
                }
            }
        }
    }
}

// ---------------- down grouped MFMA GEMM: y[pair] = h[pair] @ Wd^T ----------------
#define DN_BM 64
#define DN_BN 128
#define DN_BK 64

__global__ __launch_bounds__(256) void down_mfma(
    const __hip_bfloat16* __restrict__ h_buf, const float* __restrict__ wd,
    const int* __restrict__ counts, const int* __restrict__ slot_list,
    float* __restrict__ ybuf)
{
    __shared__ short Hs[DN_BM * LDK];
    __shared__ short Ws[DN_BN * LDK];

    int e = blockIdx.y;
    int n_e = counts[e];
    if (n_e == 0) return;
    int dbase = blockIdx.x * DN_BN;
    const float* WD = wd + (size_t)e * DIM * HID;
    const int* sl = slot_list + e * NTOK;

    int tid = threadIdx.x;
    int lane = tid & 63;
    int wave = tid >> 6;
    int wm = wave >> 1;
    int wn = wave & 1;
    int fr = lane & 15;
    int fq = lane >> 4;

    for (int m0 = blockIdx.z * DN_BM; m0 < n_e; m0 += gridDim.z * DN_BM) {
        int rows = n_e - m0; if (rows > DN_BM) rows = DN_BM;
        f32x4 acc[2][4];
#pragma unroll
        for (int i = 0; i < 2; ++i)
#pragma unroll
            for (int j = 0; j < 4; ++j) acc[i][j] = (f32x4)(0.f);

        for (int k0 = 0; k0 < HID; k0 += DN_BK) {
            // stage H tile (bf16 already; gathered rows); 512 16B-chunks, 2 per thread
#pragma unroll
            for (int p = 0; p < 2; ++p) {
                int idx = p * 256 + tid;      // 0..511
                int r = idx >> 3;             // 0..63
                int c8 = idx & 7;             // bf16x8 within row
                bf16x8 v = (bf16x8)(short)0;
                if (r < rows) {
                    int slot = sl[m0 + r];
                    v = *(const bf16x8*)(h_buf + (size_t)slot * HID + k0 + c8 * 8);
                }
                *(bf16x8*)&Hs[r * LDK + c8 * 8] = v;
            }
            // stage WD tile (f32 -> bf16)
#pragma unroll
            for (int p = 0; p < 8; ++p) {
                int idx = p * 256 + tid;      // 0..2047
                int r = idx >> 4;             // 0..127
                int c4 = idx & 15;
                f32x4 wv = *(const f32x4*)(WD + (size_t)(dbase + r) * HID + k0 + c4 * 4);
                *(bf16x4*)&Ws[r * LDK + c4 * 4] = cvt4(wv);
            }
            __syncthreads();
#pragma unroll
            for (int kk = 0; kk < 2; ++kk) {
                int kof = kk * 32 + fq * 8;
                bf16x8 a[2], b[4];
#pragma unroll
                for (int i = 0; i < 2; ++i)
                    a[i] = *(const bf16x8*)&Hs[(wm * 32 + i * 16 + fr) * LDK + kof];
#pragma unroll
                for (int j = 0; j < 4; ++j)
                    b[j] = *(const bf16x8*)&Ws[(wn * 64 + j * 16 + fr) * LDK + kof];
#pragma unroll
                for (int i = 0; i < 2; ++i)
#pragma unroll
                    for (int j = 0; j < 4; ++j)
                        acc[i][j] = __builtin_amdgcn_mfma_f32_16x16x32_bf16(a[i], b[j], acc[i][j], 0, 0, 0);
            }
            __syncthreads();
        }
        // epilogue: y (f32) scattered by slot
#pragma unroll
        for (int i = 0; i < 2; ++i) {
            int rbase = wm * 32 + i * 16 + fq * 4;
#pragma unroll
            for (int reg = 0; reg < 4; ++reg) {
                int r = rbase + reg;
                if (m0 + r < n_e) {
                    int slot = sl[m0 + r];
#pragma unroll
                    for (int j = 0; j < 4; ++j)
                        ybuf[(size_t)slot * DIM + dbase + wn * 64 + j * 16 + fr] = acc[i][j][reg];
                }
            }
        }
    }
}

// ---------------- combine: out[t] = y[2t] + y[2t+1] ----------------
__global__ __launch_bounds__(256) void combine_kernel(const float* __restrict__ ybuf, float* __restrict__ out)
{
    int i = blockIdx.x * 256 + threadIdx.x;
    int t = i >> 8;
    int c = i & 255;
    const float4* ya = (const float4*)(ybuf + (size_t)(2 * t) * DIM) + c;
    const float4* yb = (const float4*)(ybuf + (size_t)(2 * t + 1) * DIM) + c;
    float4 a = *ya, b = *yb, r;
    r.x = a.x + b.x; r.y = a.y + b.y; r.z = a.z + b.z; r.w = a.w + b.w;
    ((float4*)(out + (size_t)t * DIM))[c] = r;
}

extern "C" void kernel_launch(void* const* d_in, const int* in_sizes, int n_in,
                              void* d_out, int out_size, void* d_ws, size_t ws_size,
                              hipStream_t stream) {
    const float* x  = (const float*)d_in[0];
    const float* rw = (const float*)d_in[1];
    const float* wg = (const float*)d_in[2];
    const float* wu = (const float*)d_in[3];
    const float* wd = (const float*)d_in[4];
    float* out = (float*)d_out;

    char* ws = (char*)d_ws;
    int* counts            = (int*)ws;                                  // 256 B
    int* slot_list         = (int*)(ws + 256);                          // 32 KB
    float* w_list          = (float*)(ws + 256 + NEXP * NTOK * 4);      // 32 KB
    __hip_bfloat16* h_buf  = (__hip_bfloat16*)(ws + 256 + 2 * NEXP * NTOK * 4);         // 2048*2048*2 = 8 MB
    float* ybuf            = (float*)((char*)h_buf + (size_t)NTOK * TOPK * HID * 2);    // 8 MB

    hipMemsetAsync(counts, 0, NEXP * sizeof(int), stream);
    router_kernel<<<NTOK, 64, 0, stream>>>(x, rw, counts, slot_list, w_list);
    gateup_mfma<<<dim3(HID / GU_BN, NEXP, 4), 256, 0, stream>>>(x, wg, wu, counts, slot_list, w_list, h_buf);
    down_mfma<<<dim3(DIM / DN_BN, NEXP, 4), 256, 0, stream>>>(h_buf, wd, counts, slot_list, ybuf);
    combine_kernel<<<NTOK * DIM / 4 / 256, 256, 0, stream>>>(ybuf, out);
}

// Round 3
// 230.926 us; speedup vs baseline: 2.0296x; 1.2902x over previous
//
#include <hip/hip_runtime.h>
#include <hip/hip_bf16.h>
#include <math.h>

#define DIM 1024
#define HID 2048
#define NEXP 8
#define NTOK 1024   // B*T
#define TOPK 2

typedef __attribute__((ext_vector_type(4))) float f32x4;
typedef __attribute__((ext_vector_type(8))) short bf16x8;
typedef __attribute__((ext_vector_type(4))) short bf16x4;

__device__ inline bf16x4 cvt4(f32x4 v) {
    bf16x4 r;
#pragma unroll
    for (int i = 0; i < 4; ++i) {
        union { float f; unsigned u; } t; t.f = v[i];
        unsigned b = t.u + 0x7fffu + ((t.u >> 16) & 1u);   // round-to-nearest-even
        r[i] = (short)(b >> 16);
    }
    return r;
}

// ---------------- router: logits -> top2 -> renormalized weights -> expert lists ----------------
__global__ __launch_bounds__(64) void router_kernel(
    const float* __restrict__ x, const float* __restrict__ rw,
    int* __restrict__ counts, int* __restrict__ slot_list, float* __restrict__ w_list)
{
    int t = blockIdx.x;
    int lane = threadIdx.x;
    const float* xr = x + (size_t)t * DIM;
    float acc[NEXP];
#pragma unroll
    for (int e = 0; e < NEXP; ++e) acc[e] = 0.f;
    for (int d = lane; d < DIM; d += 64) {
        float xv = xr[d];
#pragma unroll
        for (int e = 0; e < NEXP; ++e) acc[e] += xv * rw[e * DIM + d];
    }
#pragma unroll
    for (int off = 32; off > 0; off >>= 1) {
#pragma unroll
        for (int e = 0; e < NEXP; ++e) acc[e] += __shfl_down(acc[e], off, 64);
    }
    if (lane == 0) {
        int i1 = 0;
#pragma unroll
        for (int e = 1; e < NEXP; ++e) if (acc[e] > acc[i1]) i1 = e;
        int i2 = -1;
#pragma unroll
        for (int e = 0; e < NEXP; ++e) {
            if (e == i1) continue;
            if (i2 < 0 || acc[e] > acc[i2]) i2 = e;
        }
        float w1 = 1.f / (1.f + expf(acc[i2] - acc[i1]));   // softmax renorm over top-2
        float w2 = 1.f - w1;
        int p1 = atomicAdd(&counts[i1], 1);
        slot_list[i1 * NTOK + p1] = t * 2 + 0;
        w_list[i1 * NTOK + p1] = w1;
        int p2 = atomicAdd(&counts[i2], 1);
        slot_list[i2 * NTOK + p2] = t * 2 + 1;
        w_list[i2 * NTOK + p2] = w2;
    }
}

// ---------------- gate+up grouped MFMA GEMM: h = w_pair * silu(x@Wg^T) * (x@Wu^T), bf16 out ----------------
// 64x64x64 tile, 4 waves (2x2), each wave a 32x32 output block; ~27.6KB LDS -> 4-5 blocks/CU
#define BM 64
#define BN 64
#define BK 64
#define LDK 72   // padded K-stride (shorts); 144B rows

__global__ __launch_bounds__(256) void gateup_mfma(
    const float* __restrict__ x, const float* __restrict__ wg, const float* __restrict__ wu,
    const int* __restrict__ counts, const int* __restrict__ slot_list, const float* __restrict__ w_list,
    __hip_bfloat16* __restrict__ h_buf)
{
    __shared__ short Xs[BM * LDK];
    __shared__ short Gs[BN * LDK];
    __shared__ short Us[BN * LDK];

    int e = blockIdx.y;
    int n_e = counts[e];
    if (n_e == 0) return;
    int hbase = blockIdx.x * BN;
    const float* WG = wg + (size_t)e * HID * DIM;
    const float* WU = wu + (size_t)e * HID * DIM;
    const int* sl = slot_list + e * NTOK;
    const float* wl = w_list + e * NTOK;

    int tid = threadIdx.x;
    int lane = tid & 63;
    int wave = tid >> 6;
    int wm = wave >> 1;      // 0..1 (token dir, 32 rows)
    int wn = wave & 1;       // 0..1 (h dir, 32 cols)
    int fr = lane & 15;
    int fq = lane >> 4;      // 0..3

    for (int m0 = blockIdx.z * BM; m0 < n_e; m0 += gridDim.z * BM) {
        int rows = n_e - m0; if (rows > BM) rows = BM;
        f32x4 accg[2][2], accu[2][2];
#pragma unroll
        for (int i = 0; i < 2; ++i)
#pragma unroll
            for (int j = 0; j < 2; ++j) { accg[i][j] = (f32x4)(0.f); accu[i][j] = (f32x4)(0.f); }

        for (int k0 = 0; k0 < DIM; k0 += BK) {
            // stage X tile (gathered rows, f32 -> bf16): 64x64
#pragma unroll
            for (int p = 0; p < 4; ++p) {
                int idx = p * 256 + tid;      // 0..1023
                int r = idx >> 4;             // 0..63
                int c4 = idx & 15;            // float4 within row
                f32x4 v = (f32x4)(0.f);
                if (r < rows) {
                    int tok = sl[m0 + r] >> 1;
                    v = *(const f32x4*)(x + (size_t)tok * DIM + k0 + c4 * 4);
                }
                *(bf16x4*)&Xs[r * LDK + c4 * 4] = cvt4(v);
            }
            // stage WG / WU tiles (f32 -> bf16): 64x64 each
#pragma unroll
            for (int p = 0; p < 4; ++p) {
                int idx = p * 256 + tid;
                int r = idx >> 4;
                int c4 = idx & 15;
                f32x4 g = *(const f32x4*)(WG + (size_t)(hbase + r) * DIM + k0 + c4 * 4);
                f32x4 u = *(const f32x4*)(WU + (size_t)(hbase + r) * DIM + k0 + c4 * 4);
                *(bf16x4*)&Gs[r * LDK + c4 * 4] = cvt4(g);
                *(bf16x4*)&Us[r * LDK + c4 * 4] = cvt4(u);
            }
            __syncthreads();
#pragma unroll
            for (int kk = 0; kk < 2; ++kk) {
                int kof = kk * 32 + fq * 8;
                bf16x8 a[2], bg[2], bu[2];
#pragma unroll
                for (int i = 0; i < 2; ++i)
                    a[i] = *(const bf16x8*)&Xs[(wm * 32 + i * 16 + fr) * LDK + kof];
#pragma unroll
                for (int j = 0; j < 2; ++j) {
                    bg[j] = *(const bf16x8*)&Gs[(wn * 32 + j * 16 + fr) * LDK + kof];
                    bu[j] = *(const bf16x8*)&Us[(wn * 32 + j * 16 + fr) * LDK + kof];
                }
#pragma unroll
                for (int i = 0; i < 2; ++i)
#pragma unroll
                    for (int j = 0; j < 2; ++j) {
                        accg[i][j] = __builtin_amdgcn_mfma_f32_16x16x32_bf16(a[i], bg[j], accg[i][j], 0, 0, 0);
                        accu[i][j] = __builtin_amdgcn_mfma_f32_16x16x32_bf16(a[i], bu[j], accu[i][j], 0, 0, 0);
                    }
            }
            __syncthreads();
        }
        // epilogue: h = w * silu(g) * u  -> bf16 h_buf[slot][h]
#pragma unroll
        for (int i = 0; i < 2; ++i) {
            int rbase = wm * 32 + i * 16 + fq * 4;
#pragma unroll
            for (int reg = 0; reg < 4; ++reg) {
                int r = rbase + reg;
                if (m0 + r < n_e) {
                    int slot = sl[m0 + r];
                    float w = wl[m0 + r];
#pragma unroll
                    for (int j = 0; j < 2; ++j) {
                        float g = accg[i][j][reg];
                        float u = accu[i][j][reg];
                        float h = w * (g / (1.f + expf(-g))) * u;
                        h_buf[(size_t)slot * HID + hbase + wn * 32 + j * 16 + fr] = __float2bfloat16(h);
                    }
                }
            }
        }
    }
}

// ---------------- down grouped MFMA GEMM: y[pair] = h[pair] @ Wd^T ----------------
__global__ __launch_bounds__(256) void down_mfma(
    const __hip_bfloat16* __restrict__ h_buf, const float* __restrict__ wd,
    const int* __restrict__ counts, const int* __restrict__ slot_list,
    float* __restrict__ ybuf)
{
    __shared__ short Hs[BM * LDK];
    __shared__ short Ws[BN * LDK];

    int e = blockIdx.y;
    int n_e = counts[e];
    if (n_e == 0) return;
    int dbase = blockIdx.x * BN;
    const float* WD = wd + (size_t)e * DIM * HID;
    const int* sl = slot_list + e * NTOK;

    int tid = threadIdx.x;
    int lane = tid & 63;
    int wave = tid >> 6;
    int wm = wave >> 1;
    int wn = wave & 1;
    int fr = lane & 15;
    int fq = lane >> 4;

    for (int m0 = blockIdx.z * BM; m0 < n_e; m0 += gridDim.z * BM) {
        int rows = n_e - m0; if (rows > BM) rows = BM;
        f32x4 acc[2][2];
#pragma unroll
        for (int i = 0; i < 2; ++i)
#pragma unroll
            for (int j = 0; j < 2; ++j) acc[i][j] = (f32x4)(0.f);

        for (int k0 = 0; k0 < HID; k0 += BK) {
            // stage H tile (bf16 already; gathered rows): 64x64 = 512 bf16x8 chunks
#pragma unroll
            for (int p = 0; p < 2; ++p) {
                int idx = p * 256 + tid;      // 0..511
                int r = idx >> 3;             // 0..63
                int c8 = idx & 7;             // bf16x8 within row
                bf16x8 v = (bf16x8)(short)0;
                if (r < rows) {
                    int slot = sl[m0 + r];
                    v = *(const bf16x8*)(h_buf + (size_t)slot * HID + k0 + c8 * 8);
                }
                *(bf16x8*)&Hs[r * LDK + c8 * 8] = v;
            }
            // stage WD tile (f32 -> bf16): 64x64
#pragma unroll
            for (int p = 0; p < 4; ++p) {
                int idx = p * 256 + tid;
                int r = idx >> 4;
                int c4 = idx & 15;
                f32x4 wv = *(const f32x4*)(WD + (size_t)(dbase + r) * HID + k0 + c4 * 4);
                *(bf16x4*)&Ws[r * LDK + c4 * 4] = cvt4(wv);
            }
            __syncthreads();
#pragma unroll
            for (int kk = 0; kk < 2; ++kk) {
                int kof = kk * 32 + fq * 8;
                bf16x8 a[2], b[2];
#pragma unroll
                for (int i = 0; i < 2; ++i)
                    a[i] = *(const bf16x8*)&Hs[(wm * 32 + i * 16 + fr) * LDK + kof];
#pragma unroll
                for (int j = 0; j < 2; ++j)
                    b[j] = *(const bf16x8*)&Ws[(wn * 32 + j * 16 + fr) * LDK + kof];
#pragma unroll
                for (int i = 0; i < 2; ++i)
#pragma unroll
                    for (int j = 0; j < 2; ++j)
                        acc[i][j] = __builtin_amdgcn_mfma_f32_16x16x32_bf16(a[i], b[j], acc[i][j], 0, 0, 0);
            }
            __syncthreads();
        }
        // epilogue: y (f32) scattered by slot
#pragma unroll
        for (int i = 0; i < 2; ++i) {
            int rbase = wm * 32 + i * 16 + fq * 4;
#pragma unroll
            for (int reg = 0; reg < 4; ++reg) {
                int r = rbase + reg;
                if (m0 + r < n_e) {
                    int slot = sl[m0 + r];
#pragma unroll
                    for (int j = 0; j < 2; ++j)
                        ybuf[(size_t)slot * DIM + dbase + wn * 32 + j * 16 + fr] = acc[i][j][reg];
                }
            }
        }
    }
}

// ---------------- combine: out[t] = y[2t] + y[2t+1] ----------------
__global__ __launch_bounds__(256) void combine_kernel(const float* __restrict__ ybuf, float* __restrict__ out)
{
    int i = blockIdx.x * 256 + threadIdx.x;
    int t = i >> 8;
    int c = i & 255;
    const float4* ya = (const float4*)(ybuf + (size_t)(2 * t) * DIM) + c;
    const float4* yb = (const float4*)(ybuf + (size_t)(2 * t + 1) * DIM) + c;
    float4 a = *ya, b = *yb, r;
    r.x = a.x + b.x; r.y = a.y + b.y; r.z = a.z + b.z; r.w = a.w + b.w;
    ((float4*)(out + (size_t)t * DIM))[c] = r;
}

extern "C" void kernel_launch(void* const* d_in, const int* in_sizes, int n_in,
                              void* d_out, int out_size, void* d_ws, size_t ws_size,
                              hipStream_t stream) {
    const float* x  = (const float*)d_in[0];
    const float* rw = (const float*)d_in[1];
    const float* wg = (const float*)d_in[2];
    const float* wu = (const float*)d_in[3];
    const float* wd = (const float*)d_in[4];
    float* out = (float*)d_out;

    char* ws = (char*)d_ws;
    int* counts            = (int*)ws;                                  // 256 B
    int* slot_list         = (int*)(ws + 256);                          // 32 KB
    float* w_list          = (float*)(ws + 256 + NEXP * NTOK * 4);      // 32 KB
    __hip_bfloat16* h_buf  = (__hip_bfloat16*)(ws + 256 + 2 * NEXP * NTOK * 4);         // 8 MB
    float* ybuf            = (float*)((char*)h_buf + (size_t)NTOK * TOPK * HID * 2);    // 8 MB

    hipMemsetAsync(counts, 0, NEXP * sizeof(int), stream);
    router_kernel<<<NTOK, 64, 0, stream>>>(x, rw, counts, slot_list, w_list);
    gateup_mfma<<<dim3(HID / BN, NEXP, 4), 256, 0, stream>>>(x, wg, wu, counts, slot_list, w_list, h_buf);
    down_mfma<<<dim3(DIM / BN, NEXP, 8), 256, 0, stream>>>(h_buf, wd, counts, slot_list, ybuf);
    combine_kernel<<<NTOK * DIM / 4 / 256, 256, 0, stream>>>(ybuf, out);
}

// Round 4
// 164.899 us; speedup vs baseline: 2.8422x; 1.4004x over previous
//
#include <hip/hip_runtime.h>
#include <hip/hip_bf16.h>
#include <math.h>

#define DIM 1024
#define HID 2048
#define NEXP 8
#define NTOK 1024   // B*T
#define TOPK 2

typedef __attribute__((ext_vector_type(4))) float f32x4;
typedef __attribute__((ext_vector_type(8))) short bf16x8;
typedef __attribute__((ext_vector_type(4))) short bf16x4;

__device__ inline bf16x4 cvt4(f32x4 v) {
    bf16x4 r;
#pragma unroll
    for (int i = 0; i < 4; ++i) {
        union { float f; unsigned u; } t; t.f = v[i];
        unsigned b = t.u + 0x7fffu + ((t.u >> 16) & 1u);   // round-to-nearest-even
        r[i] = (short)(b >> 16);
    }
    return r;
}

// ---------------- x -> bf16 pre-convert (4MB -> 2MB, once per launch) ----------------
__global__ __launch_bounds__(256) void xcvt_kernel(const float* __restrict__ x, __hip_bfloat16* __restrict__ xb)
{
    int i = blockIdx.x * 256 + threadIdx.x;   // over NTOK*DIM/4
    f32x4 v = *(const f32x4*)(x + (size_t)i * 4);
    *(bf16x4*)(xb + (size_t)i * 4) = cvt4(v);
}

// ---------------- router: logits -> top2 -> renormalized weights -> expert lists ----------------
__global__ __launch_bounds__(64) void router_kernel(
    const float* __restrict__ x, const float* __restrict__ rw,
    int* __restrict__ counts, int* __restrict__ slot_list, float* __restrict__ w_list)
{
    int t = blockIdx.x;
    int lane = threadIdx.x;
    const float* xr = x + (size_t)t * DIM;
    float acc[NEXP];
#pragma unroll
    for (int e = 0; e < NEXP; ++e) acc[e] = 0.f;
    for (int d = lane; d < DIM; d += 64) {
        float xv = xr[d];
#pragma unroll
        for (int e = 0; e < NEXP; ++e) acc[e] += xv * rw[e * DIM + d];
    }
#pragma unroll
    for (int off = 32; off > 0; off >>= 1) {
#pragma unroll
        for (int e = 0; e < NEXP; ++e) acc[e] += __shfl_down(acc[e], off, 64);
    }
    if (lane == 0) {
        int i1 = 0;
#pragma unroll
        for (int e = 1; e < NEXP; ++e) if (acc[e] > acc[i1]) i1 = e;
        int i2 = -1;
#pragma unroll
        for (int e = 0; e < NEXP; ++e) {
            if (e == i1) continue;
            if (i2 < 0 || acc[e] > acc[i2]) i2 = e;
        }
        float w1 = 1.f / (1.f + expf(acc[i2] - acc[i1]));   // softmax renorm over top-2
        float w2 = 1.f - w1;
        int p1 = atomicAdd(&counts[i1], 1);
        slot_list[i1 * NTOK + p1] = t * 2 + 0;
        w_list[i1 * NTOK + p1] = w1;
        int p2 = atomicAdd(&counts[i2], 1);
        slot_list[i2 * NTOK + p2] = t * 2 + 1;
        w_list[i2 * NTOK + p2] = w2;
    }
}

#define LDK 72        // padded LDS row stride in shorts (144B)
#define MBLK 128      // token rows per block-iter

// ---------------- gate+up grouped MFMA GEMM, 2-stage reg-prefetch pipeline ----------------
// grid: 512 blocks = (p in [0,256) = e*32+hb) x (z in {0,1}); bid maps z-pair to SAME XCD.
__global__ __launch_bounds__(256, 2) void gateup_mfma(
    const __hip_bfloat16* __restrict__ xb, const float* __restrict__ wg, const float* __restrict__ wu,
    const int* __restrict__ counts, const int* __restrict__ slot_list, const float* __restrict__ w_list,
    __hip_bfloat16* __restrict__ h_buf)
{
    __shared__ short Xs[2][MBLK * LDK];   // 36 KB
    __shared__ short Gs[2][64 * LDK];     // 18 KB
    __shared__ short Us[2][64 * LDK];     // 18 KB

    int bid = blockIdx.x;
    int pl = bid & 7, s = bid >> 3;
    int z = s & 1, ph = s >> 1;
    int p = (ph << 3) + pl;              // 0..255
    int e = p >> 5;
    int hbase = (p & 31) * 64;

    int n_e = counts[e];
    const float* WG = wg + (size_t)e * HID * DIM;
    const float* WU = wu + (size_t)e * HID * DIM;
    const int* sl = slot_list + e * NTOK;
    const float* wl = w_list + e * NTOK;

    int tid = threadIdx.x;
    int lane = tid & 63;
    int wn = tid >> 6;                   // wave id = 16-col subtile
    int fr = lane & 15, fq = lane >> 4;

    int c8 = tid & 7;                    // X staging: 16B chunk within row
    int xrr = tid >> 3;                  // X staging: base row (0..31), +32 per p_
    int c4 = tid & 15;                   // W staging: f32x4 chunk within row
    int wrr = tid >> 4;                  // W staging: base row (0..15), +16 per p_

    for (int m0 = z * MBLK; m0 < n_e; m0 += 2 * MBLK) {
        int rows = n_e - m0; if (rows > MBLK) rows = MBLK;

        // hoist per-thread source pointers
        const __hip_bfloat16* xsrc[4];
#pragma unroll
        for (int p_ = 0; p_ < 4; ++p_) {
            int r = p_ * 32 + xrr;
            xsrc[p_] = (r < rows) ? (xb + (size_t)(sl[m0 + r] >> 1) * DIM + c8 * 8) : (const __hip_bfloat16*)0;
        }
        const float* gsrc[4]; const float* usrc[4];
#pragma unroll
        for (int p_ = 0; p_ < 4; ++p_) {
            int r = p_ * 16 + wrr;
            gsrc[p_] = WG + (size_t)(hbase + r) * DIM + c4 * 4;
            usrc[p_] = WU + (size_t)(hbase + r) * DIM + c4 * 4;
        }

        // prefetch step 0
        bf16x8 xr[4]; f32x4 gr[4], ur[4];
#pragma unroll
        for (int p_ = 0; p_ < 4; ++p_) {
            bf16x8 xv = (bf16x8)(short)0;
            if (xsrc[p_]) xv = *(const bf16x8*)(xsrc[p_]);
            xr[p_] = xv;
            gr[p_] = *(const f32x4*)(gsrc[p_]);
            ur[p_] = *(const f32x4*)(usrc[p_]);
        }

        f32x4 accg[8], accu[8];
#pragma unroll
        for (int ms = 0; ms < 8; ++ms) { accg[ms] = (f32x4)(0.f); accu[ms] = (f32x4)(0.f); }

#pragma unroll 1
        for (int t = 0; t < DIM / 64; ++t) {
            int cur = t & 1;
            // write staged regs -> LDS[cur]
#pragma unroll
            for (int p_ = 0; p_ < 4; ++p_)
                *(bf16x8*)&Xs[cur][(p_ * 32 + xrr) * LDK + c8 * 8] = xr[p_];
#pragma unroll
            for (int p_ = 0; p_ < 4; ++p_) {
                *(bf16x4*)&Gs[cur][(p_ * 16 + wrr) * LDK + c4 * 4] = cvt4(gr[p_]);
                *(bf16x4*)&Us[cur][(p_ * 16 + wrr) * LDK + c4 * 4] = cvt4(ur[p_]);
            }
            __syncthreads();
            // issue next step's loads (latency hides under MFMA below)
            if (t + 1 < DIM / 64) {
                int ko = (t + 1) * 64;
#pragma unroll
                for (int p_ = 0; p_ < 4; ++p_) {
                    bf16x8 xv = (bf16x8)(short)0;
                    if (xsrc[p_]) xv = *(const bf16x8*)(xsrc[p_] + ko);
                    xr[p_] = xv;
                    gr[p_] = *(const f32x4*)(gsrc[p_] + ko);
                    ur[p_] = *(const f32x4*)(usrc[p_] + ko);
                }
            }
            // compute on LDS[cur]
#pragma unroll
            for (int kk = 0; kk < 2; ++kk) {
                int kof = kk * 32 + fq * 8;
                bf16x8 bg = *(const bf16x8*)&Gs[cur][(wn * 16 + fr) * LDK + kof];
                bf16x8 bu = *(const bf16x8*)&Us[cur][(wn * 16 + fr) * LDK + kof];
#pragma unroll
                for (int ms = 0; ms < 8; ++ms) {
                    bf16x8 a = *(const bf16x8*)&Xs[cur][(ms * 16 + fr) * LDK + kof];
                    accg[ms] = __builtin_amdgcn_mfma_f32_16x16x32_bf16(a, bg, accg[ms], 0, 0, 0);
                    accu[ms] = __builtin_amdgcn_mfma_f32_16x16x32_bf16(a, bu, accu[ms], 0, 0, 0);
                }
            }
            __syncthreads();
        }

        // epilogue: h = w * silu(g) * u -> bf16
#pragma unroll
        for (int ms = 0; ms < 8; ++ms) {
#pragma unroll
            for (int reg = 0; reg < 4; ++reg) {
                int r = ms * 16 + fq * 4 + reg;
                if (r < rows) {
                    int slot = sl[m0 + r];
                    float w = wl[m0 + r];
                    float g = accg[ms][reg], u = accu[ms][reg];
                    float h = w * (g / (1.f + expf(-g))) * u;
                    h_buf[(size_t)slot * HID + hbase + wn * 16 + fr] = __float2bfloat16(h);
                }
            }
        }
    }
}

// ---------------- down grouped MFMA GEMM: y[pair] = h[pair] @ Wd^T ----------------
// grid: 256 blocks = (q in [0,128) = e*16+db) x (z in {0,1}); z-pair on same XCD.
__global__ __launch_bounds__(256, 2) void down_mfma(
    const __hip_bfloat16* __restrict__ h_buf, const float* __restrict__ wd,
    const int* __restrict__ counts, const int* __restrict__ slot_list,
    float* __restrict__ ybuf)
{
    __shared__ short Hs[2][MBLK * LDK];   // 36 KB
    __shared__ short Ws[2][64 * LDK];     // 18 KB

    int bid = blockIdx.x;
    int pl = bid & 7, s = bid >> 3;
    int z = s & 1, ph = s >> 1;
    int q = (ph << 3) + pl;              // 0..127
    int e = q >> 4;
    int dbase = (q & 15) * 64;

    int n_e = counts[e];
    const float* WD = wd + (size_t)e * DIM * HID;
    const int* sl = slot_list + e * NTOK;

    int tid = threadIdx.x;
    int lane = tid & 63;
    int wn = tid >> 6;
    int fr = lane & 15, fq = lane >> 4;

    int c8 = tid & 7;
    int hrr = tid >> 3;
    int c4 = tid & 15;
    int wrr = tid >> 4;

    for (int m0 = z * MBLK; m0 < n_e; m0 += 2 * MBLK) {
        int rows = n_e - m0; if (rows > MBLK) rows = MBLK;

        const __hip_bfloat16* hsrc[4];
#pragma unroll
        for (int p_ = 0; p_ < 4; ++p_) {
            int r = p_ * 32 + hrr;
            hsrc[p_] = (r < rows) ? (h_buf + (size_t)sl[m0 + r] * HID + c8 * 8) : (const __hip_bfloat16*)0;
        }
        const float* wsrc[4];
#pragma unroll
        for (int p_ = 0; p_ < 4; ++p_)
            wsrc[p_] = WD + (size_t)(dbase + p_ * 16 + wrr) * HID + c4 * 4;

        bf16x8 hr_[4]; f32x4 wr_[4];
#pragma unroll
        for (int p_ = 0; p_ < 4; ++p_) {
            bf16x8 hv = (bf16x8)(short)0;
            if (hsrc[p_]) hv = *(const bf16x8*)(hsrc[p_]);
            hr_[p_] = hv;
            wr_[p_] = *(const f32x4*)(wsrc[p_]);
        }

        f32x4 acc[8];
#pragma unroll
        for (int ms = 0; ms < 8; ++ms) acc[ms] = (f32x4)(0.f);

#pragma unroll 1
        for (int t = 0; t < HID / 64; ++t) {
            int cur = t & 1;
#pragma unroll
            for (int p_ = 0; p_ < 4; ++p_)
                *(bf16x8*)&Hs[cur][(p_ * 32 + hrr) * LDK + c8 * 8] = hr_[p_];
#pragma unroll
            for (int p_ = 0; p_ < 4; ++p_)
                *(bf16x4*)&Ws[cur][(p_ * 16 + wrr) * LDK + c4 * 4] = cvt4(wr_[p_]);
            __syncthreads();
            if (t + 1 < HID / 64) {
                int ko = (t + 1) * 64;
#pragma unroll
                for (int p_ = 0; p_ < 4; ++p_) {
                    bf16x8 hv = (bf16x8)(short)0;
                    if (hsrc[p_]) hv = *(const bf16x8*)(hsrc[p_] + ko);
                    hr_[p_] = hv;
                    wr_[p_] = *(const f32x4*)(wsrc[p_] + ko);
                }
            }
#pragma unroll
            for (int kk = 0; kk < 2; ++kk) {
                int kof = kk * 32 + fq * 8;
                bf16x8 b = *(const bf16x8*)&Ws[cur][(wn * 16 + fr) * LDK + kof];
#pragma unroll
                for (int ms = 0; ms < 8; ++ms) {
                    bf16x8 a = *(const bf16x8*)&Hs[cur][(ms * 16 + fr) * LDK + kof];
                    acc[ms] = __builtin_amdgcn_mfma_f32_16x16x32_bf16(a, b, acc[ms], 0, 0, 0);
                }
            }
            __syncthreads();
        }

#pragma unroll
        for (int ms = 0; ms < 8; ++ms) {
#pragma unroll
            for (int reg = 0; reg < 4; ++reg) {
                int r = ms * 16 + fq * 4 + reg;
                if (r < rows) {
                    int slot = sl[m0 + r];
                    ybuf[(size_t)slot * DIM + dbase + wn * 16 + fr] = acc[ms][reg];
                }
            }
        }
    }
}

// ---------------- combine: out[t] = y[2t] + y[2t+1] ----------------
__global__ __launch_bounds__(256) void combine_kernel(const float* __restrict__ ybuf, float* __restrict__ out)
{
    int i = blockIdx.x * 256 + threadIdx.x;
    int t = i >> 8;
    int c = i & 255;
    const float4* ya = (const float4*)(ybuf + (size_t)(2 * t) * DIM) + c;
    const float4* yb = (const float4*)(ybuf + (size_t)(2 * t + 1) * DIM) + c;
    float4 a = *ya, b = *yb, r;
    r.x = a.x + b.x; r.y = a.y + b.y; r.z = a.z + b.z; r.w = a.w + b.w;
    ((float4*)(out + (size_t)t * DIM))[c] = r;
}

extern "C" void kernel_launch(void* const* d_in, const int* in_sizes, int n_in,
                              void* d_out, int out_size, void* d_ws, size_t ws_size,
                              hipStream_t stream) {
    const float* x  = (const float*)d_in[0];
    const float* rw = (const float*)d_in[1];
    const float* wg = (const float*)d_in[2];
    const float* wu = (const float*)d_in[3];
    const float* wd = (const float*)d_in[4];
    float* out = (float*)d_out;

    char* ws = (char*)d_ws;
    int* counts            = (int*)ws;                                   // 256 B
    int* slot_list         = (int*)(ws + 256);                           // 32 KB
    float* w_list          = (float*)(ws + 256 + NEXP * NTOK * 4);       // 32 KB
    __hip_bfloat16* xb     = (__hip_bfloat16*)(ws + 256 + 2 * NEXP * NTOK * 4);       // 2 MB
    __hip_bfloat16* h_buf  = (__hip_bfloat16*)((char*)xb + (size_t)NTOK * DIM * 2);   // 8 MB
    float* ybuf            = (float*)((char*)h_buf + (size_t)NTOK * TOPK * HID * 2);  // 8 MB

    hipMemsetAsync(counts, 0, NEXP * sizeof(int), stream);
    xcvt_kernel<<<NTOK * DIM / 4 / 256, 256, 0, stream>>>(x, xb);
    router_kernel<<<NTOK, 64, 0, stream>>>(x, rw, counts, slot_list, w_list);
    gateup_mfma<<<512, 256, 0, stream>>>(xb, wg, wu, counts, slot_list, w_list, h_buf);
    down_mfma<<<256, 256, 0, stream>>>(h_buf, wd, counts, slot_list, ybuf);
    combine_kernel<<<NTOK * DIM / 4 / 256, 256, 0, stream>>>(ybuf, out);
}